// Round 9
// baseline (132.004 us; speedup 1.0000x reference)
//
#include <hip/hip_runtime.h>
#include <math.h>

// Problem constants (B=8, H=W=32, D=256, heads=4, hd=64)
#define NTOK   1024
#define DMODEL 256
#define NHEADS 4
#define HDIM   64
#define NROWS  8192
#define LOG2E  1.4426950408889634f

typedef __attribute__((ext_vector_type(8))) short          bf16x8;
typedef __attribute__((ext_vector_type(8))) unsigned short ushort8;
typedef __attribute__((ext_vector_type(4))) unsigned short ushort4v;
typedef __attribute__((ext_vector_type(4))) float          f32x4;

__device__ __forceinline__ unsigned short f2bf(float x) {   // RNE fp32->bf16
    unsigned u = __float_as_uint(x);
    u = (u + 0x7fffu + ((u >> 16) & 1u)) >> 16;
    return (unsigned short)u;
}

// async global->LDS DMA, 16 B per lane; LDS dest = wave-uniform base + lane*16
#define GLD_LDS16(gp, lp)                                            \
    __builtin_amdgcn_global_load_lds(                                \
        (__attribute__((address_space(1))) void*)(gp),               \
        (__attribute__((address_space(3))) void*)(lp), 16, 0, 0)

// ---------------------------------------------------------------------------
// Kernel 1 (prep): V transpose -> Vt[bh][d][key], x cast -> Xb,
// bias expand Pb3, bf16 pre-cast of Wq/Wk/Wo.  Grid (16, 32) x 256.
// ---------------------------------------------------------------------------
__global__ __launch_bounds__(256) void prep(
    const float* __restrict__ X, unsigned short* __restrict__ Vt,
    unsigned short* __restrict__ Xb,
    const float* __restrict__ bt, float* __restrict__ Pb3,
    const float* __restrict__ Wq, const float* __restrict__ Wk,
    const float* __restrict__ Wo,
    unsigned short* __restrict__ Wqb, unsigned short* __restrict__ Wkb,
    unsigned short* __restrict__ Wob)
{
    const int kt = blockIdx.x;    // 0..15 (64-key tile)
    const int bh = blockIdx.y;    // 0..31
    const int b = bh >> 2, h = bh & 3;
    const int t = threadIdx.x;
    __shared__ unsigned short T[64][80];

    const int gid = (blockIdx.y * gridDim.x + blockIdx.x) * 256 + t;  // 0..131071

    // fused bias expansion (61440 elems)
    if (gid < NHEADS * 15 * 1024) {
        const int w2 = gid & 31;
        const int w1 = (gid >> 5) & 31;
        const int rh = (gid >> 10) % 15;
        const int hh = gid / (15 * 1024);
        int rw = w1 - w2 + 7; rw = rw < 0 ? 0 : (rw > 14 ? 14 : rw);
        Pb3[gid] = bt[(rh * 15 + rw) * NHEADS + hh] * LOG2E;
    }

    // fused weight cast: 3 * 65536 elems = 24576 ushort8 granules
    if (gid < 3 * 8192) {
        const int which = gid >> 13;          // 0=Wq 1=Wk 2=Wo
        const int off   = (gid & 8191) * 8;
        const float* __restrict__ Ws = which == 0 ? Wq : (which == 1 ? Wk : Wo);
        unsigned short* __restrict__ Wd = which == 0 ? Wqb : (which == 1 ? Wkb : Wob);
        const float4 w0 = *(const float4*)&Ws[off];
        const float4 w1 = *(const float4*)&Ws[off + 4];
        ushort8 pk;
        pk[0]=f2bf(w0.x); pk[1]=f2bf(w0.y); pk[2]=f2bf(w0.z); pk[3]=f2bf(w0.w);
        pk[4]=f2bf(w1.x); pk[5]=f2bf(w1.y); pk[6]=f2bf(w1.z); pk[7]=f2bf(w1.w);
        *(ushort8*)&Wd[off] = pk;
    }

    #pragma unroll
    for (int i = 0; i < 4; i++) {
        const int tt  = t + 256 * i;       // 0..1023
        const int key = tt >> 4;           // 0..63
        const int d4  = (tt & 15) * 4;
        const long off = (long)(b*NTOK + kt*64 + key)*DMODEL + h*HDIM + d4;
        const float4 v = *(const float4*)&X[off];
        ushort4v pk;
        pk.x = f2bf(v.x); pk.y = f2bf(v.y); pk.z = f2bf(v.z); pk.w = f2bf(v.w);
        *(ushort4v*)&Xb[off] = pk;          // linear bf16 copy of x
        T[d4+0][key] = pk.x; T[d4+1][key] = pk.y;
        T[d4+2][key] = pk.z; T[d4+3][key] = pk.w;
    }
    __syncthreads();
    #pragma unroll
    for (int i = 0; i < 2; i++) {
        const int tt = t + 256 * i;        // 0..511
        const int d  = tt >> 3;            // 0..63
        const int g  = tt & 7;             // 0..7
        const ushort8 o = *(const ushort8*)&T[d][g*8];
        *(ushort8*)&Vt[(bh*HDIM + d)*NTOK + kt*64 + g*8] = o;
    }
}

// ---------------------------------------------------------------------------
// Kernel 2: MFMA projection GEMM.  C = Xb @ Wb^T (+bias) [* scale] -> bf16
// Tile 128(M) x 64(N), 4 waves.  Wb staged once in LDS via global_load_lds
// (swizzle realized by permuting each lane's global column).
// blockIdx.z: 0 -> Q (scale 0.125*log2e), 1 -> K.
// ---------------------------------------------------------------------------
__global__ __launch_bounds__(256) void gemm_proj_mfma(
    const unsigned short* __restrict__ Xb,
    const unsigned short* __restrict__ Wqb, const float* __restrict__ bq,
    const unsigned short* __restrict__ Wkb, const float* __restrict__ bk,
    unsigned short* __restrict__ Qb, unsigned short* __restrict__ Kb)
{
    const int zz = blockIdx.z;
    const unsigned short* __restrict__ Wb = zz ? Wkb : Wqb;
    const float* __restrict__ bias = zz ? bk : bq;
    unsigned short* __restrict__ C = zz ? Kb : Qb;
    const float scale = zz ? 1.0f : (0.125f * LOG2E);

    const int n0 = blockIdx.x * 64;
    const int m0 = blockIdx.y * 128;
    const int t  = threadIdx.x;
    const int wv = t >> 6, lane = t & 63;
    const int quad = lane >> 4, l16 = lane & 15;

    __shared__ unsigned short Bs[64 * 256];   // 32 KB, swizzled 16B granules

    // DMA staging: 2048 granules, wave wv covers [wv*512, +512)
    #pragma unroll
    for (int i = 0; i < 8; i++) {
        const int gr = wv*512 + i*64 + lane;
        const int n  = gr >> 5;               // 0..63
        const int gs = gr & 31;               // LDS granule slot within row
        const int g  = (gs & 24) | ((gs & 7) ^ (n & 7));   // global column granule
        GLD_LDS16(&Wb[(n0 + n)*DMODEL + g*8], &Bs[(wv*512 + i*64)*8]);
    }
    __syncthreads();

    const int rowbase = m0 + wv * 32;

    f32x4 acc[2][4];
    #pragma unroll
    for (int nf = 0; nf < 4; nf++) {
        const float bv = bias[n0 + nf*16 + l16];
        #pragma unroll
        for (int mf = 0; mf < 2; mf++) { acc[mf][nf] = (f32x4){bv,bv,bv,bv}; }
    }

    for (int ks = 0; ks < 8; ks++) {
        const bf16x8 a0 = *(const bf16x8*)&Xb[(rowbase      + l16)*DMODEL + ks*32 + quad*8];
        const bf16x8 a1 = *(const bf16x8*)&Xb[(rowbase + 16 + l16)*DMODEL + ks*32 + quad*8];
        #pragma unroll
        for (int nf = 0; nf < 4; nf++) {
            const int n = nf*16 + l16;
            const bf16x8 bfr = *(const bf16x8*)&Bs[n*256 + 8*((ks*4 + quad) ^ (n & 7))];
            acc[0][nf] = __builtin_amdgcn_mfma_f32_16x16x32_bf16(a0, bfr, acc[0][nf], 0, 0, 0);
            acc[1][nf] = __builtin_amdgcn_mfma_f32_16x16x32_bf16(a1, bfr, acc[1][nf], 0, 0, 0);
        }
    }

    #pragma unroll
    for (int mf = 0; mf < 2; mf++)
        #pragma unroll
        for (int nf = 0; nf < 4; nf++) {
            const int col = n0 + nf*16 + l16;
            #pragma unroll
            for (int r = 0; r < 4; r++) {
                const int row = rowbase + mf*16 + quad*4 + r;
                C[row*DMODEL + col] = f2bf(acc[mf][nf][r] * scale);
            }
        }
}

// ---------------------------------------------------------------------------
// Kernel 3: MFMA flash attention. Grid (16 qtiles of 64, 32 bh), 256 thr.
// Double-buffered Ks/Vs filled by ASYNC global_load_lds (issued at chunk top,
// drained by the end-of-chunk __syncthreads).  No VGPR staging round-trip.
// Swizzle preserved by permuting each lane's global column (involutive XOR).
// P round-trip: same-wave LDS (in-order DS pipe) + wave_barrier for ordering.
// S^T layout, max-free softmax, epilogue normalize, bf16 Ob out.  LDS 80 KB.
// ---------------------------------------------------------------------------
__global__ __launch_bounds__(256) void attn_mfma(
    const unsigned short* __restrict__ Qb, const unsigned short* __restrict__ Kb,
    const unsigned short* __restrict__ Vt, const float* __restrict__ Pb3,
    unsigned short* __restrict__ Ob)
{
    const int qt   = blockIdx.x;    // 0..15
    const int bh   = blockIdx.y;    // 0..31
    const int b    = bh >> 2, h = bh & 3;
    const int t    = threadIdx.x;
    const int wv   = t >> 6, lane = t & 63;
    const int quad = lane >> 4, l16 = lane & 15;

    __shared__ unsigned short Ks[2][128 * 64];  // 32 KB
    __shared__ unsigned short Vs[2][64 * 128];  // 32 KB
    __shared__ unsigned short Ps[4][16 * 128];  // 16 KB, XOR-swizzled

    const int qbase = qt * 64 + wv * 16;
    const int h1    = qbase >> 5;               // wave-uniform
    const int w1    = (qbase & 31) + l16;

    bf16x8 qa0, qa1;
    {
        const unsigned short* qp =
            &Qb[(b*NTOK + qbase + l16) * DMODEL + h*HDIM + quad*8];
        qa0 = *(const bf16x8*)(qp);
        qa1 = *(const bf16x8*)(qp + 32);
    }

    f32x4 Of[4] = {};
    float rs = 0.f;

    const unsigned short* KbBase = &Kb[(b*NTOK) * DMODEL + h*HDIM];
    const unsigned short* VtBase = &Vt[(bh*HDIM) * NTOK];
    unsigned short* Pw = Ps[wv];

    // DMA-stage a 128-key chunk (c0) into buffer pb.
    // K: 1024 granules; granule gr -> key=gr>>3, slot gs=gr&7, global col g=gs^(key&7)
    // V: 1024 granules; granule gr -> d=gr>>4, slot gs=gr&15, global key-gran gk=gs^(d&7)
    auto stage = [&](int c0, int pb) {
        #pragma unroll
        for (int i = 0; i < 4; i++) {
            const int gr  = wv*256 + i*64 + lane;
            const int key = gr >> 3, gs = gr & 7;
            const int g   = gs ^ (key & 7);
            GLD_LDS16(&KbBase[(c0 + key)*DMODEL + g*8], &Ks[pb][(wv*256 + i*64)*8]);
        }
        #pragma unroll
        for (int i = 0; i < 4; i++) {
            const int gr = wv*256 + i*64 + lane;
            const int d  = gr >> 4, gs = gr & 15;
            const int gk = gs ^ (d & 7);
            GLD_LDS16(&VtBase[d*NTOK + c0 + gk*8], &Vs[pb][(wv*256 + i*64)*8]);
        }
    };

    stage(0, 0);
    __syncthreads();          // drains vmcnt -> chunk 0 resident

    for (int ch = 0; ch < 8; ch++) {
        const int c0 = ch * 128;
        const int p  = ch & 1;

        // async DMA for chunk ch+1 into the back buffer (drained by barrier below)
        if (ch < 7) stage(c0 + 128, p ^ 1);

        // issue all 8 bias loads for this chunk up-front
        f32x4 bias_c[8];
        #pragma unroll
        for (int nt = 0; nt < 8; nt++) {
            const int nk = c0 + nt*16;
            const int h2 = nk >> 5;
            int rh = h1 - h2 + 7; rh = rh < 0 ? 0 : (rh > 14 ? 14 : rh);
            bias_c[nt] = *(const f32x4*)
                &Pb3[(((h*15 + rh)*32) + w1)*32 + (nk & 31) + quad*4];
        }

        // ---- scores: S^T tile = K_tile @ Q^T, bias preloaded in acc ----
        #pragma unroll
        for (int nt = 0; nt < 8; nt++) {
            f32x4 c = bias_c[nt];
            const int kk = nt*16 + l16;
            {
                const bf16x8 ka = *(const bf16x8*)&Ks[p][kk*64 + 8*(quad ^ (kk & 7))];
                c = __builtin_amdgcn_mfma_f32_16x16x32_bf16(ka, qa0, c, 0, 0, 0);
            }
            {
                const bf16x8 ka = *(const bf16x8*)&Ks[p][kk*64 + 8*((quad+4) ^ (kk & 7))];
                c = __builtin_amdgcn_mfma_f32_16x16x32_bf16(ka, qa1, c, 0, 0, 0);
            }
            const float p0 = exp2f(c[0]), p1 = exp2f(c[1]);
            const float p2 = exp2f(c[2]), p3 = exp2f(c[3]);
            rs += (p0 + p1) + (p2 + p3);
            uint2 pk;
            pk.x = (unsigned)f2bf(p0) | ((unsigned)f2bf(p1) << 16);
            pk.y = (unsigned)f2bf(p2) | ((unsigned)f2bf(p3) << 16);
            // P store: row=qrow=l16, keys nt*16+quad*4..+3 (swizzled granule)
            const int g = nt*2 + (quad >> 1);
            *(uint2*)&Pw[l16*128 + 8*(g ^ l16) + (quad & 1)*4] = pk;
        }
        // same-wave P write->read: DS pipe is in-order per wave; block compiler motion
        __builtin_amdgcn_wave_barrier();

        // ---- PV: O += P V ----
        #pragma unroll
        for (int ks = 0; ks < 4; ks++) {
            const bf16x8 pa = *(const bf16x8*)&Pw[l16*128 + 8*((ks*4 + quad) ^ l16)];
            #pragma unroll
            for (int dt = 0; dt < 4; dt++) {
                const int dcol = dt*16 + l16;
                const bf16x8 vb = *(const bf16x8*)
                    &Vs[p][dcol*128 + 8*((ks*4 + quad) ^ (dcol & 7))];
                Of[dt] = __builtin_amdgcn_mfma_f32_16x16x32_bf16(pa, vb, Of[dt], 0, 0, 0);
            }
        }

        // barrier: all waves done with buf p, and (via vmcnt(0) drain) chunk
        // ch+1's DMA is complete in buf p^1.
        if (ch < 7) __syncthreads();
    }

    // ---- epilogue: combine quad partial sums, normalize, store bf16 ----
    float tot = rs;
    tot += __shfl_xor(tot, 16);
    tot += __shfl_xor(tot, 32);          // all quads hold row-sum for q-row l16
    float rinv[4];
    #pragma unroll
    for (int r = 0; r < 4; r++)
        rinv[r] = 1.0f / __shfl(tot, quad*4 + r);

    #pragma unroll
    for (int dt = 0; dt < 4; dt++)
        #pragma unroll
        for (int r = 0; r < 4; r++) {
            const int row = qbase + quad*4 + r;
            Ob[(b*NTOK + row)*DMODEL + h*HDIM + dt*16 + l16] = f2bf(Of[dt][r] * rinv[r]);
        }
}

// ---------------------------------------------------------------------------
// Kernel 4: MFMA output projection + gated blend.  64x64 tile (512 blocks).
// out = x + (1-g)*pe + g*(Ob @ Wo^T + bo), fp32 out.  DMA weight staging.
// ---------------------------------------------------------------------------
__global__ __launch_bounds__(256) void gemm_out_mfma(
    const unsigned short* __restrict__ Ob,
    const unsigned short* __restrict__ Wob, const float* __restrict__ bo,
    const float* __restrict__ X, const float* __restrict__ PE,
    const float* __restrict__ gatep,
    float* __restrict__ Out)
{
    const int n0 = blockIdx.x * 64;
    const int m0 = blockIdx.y * 64;
    const int t  = threadIdx.x;
    const int wv = t >> 6, lane = t & 63;
    const int quad = lane >> 4, l16 = lane & 15;

    __shared__ unsigned short Bs[64 * 256];

    #pragma unroll
    for (int i = 0; i < 8; i++) {
        const int gr = wv*512 + i*64 + lane;
        const int n  = gr >> 5;
        const int gs = gr & 31;
        const int g  = (gs & 24) | ((gs & 7) ^ (n & 7));
        GLD_LDS16(&Wob[(n0 + n)*DMODEL + g*8], &Bs[(wv*512 + i*64)*8]);
    }
    __syncthreads();

    const int rowbase = m0 + wv * 16;

    f32x4 acc[4];
    #pragma unroll
    for (int nf = 0; nf < 4; nf++) {
        const float bv = bo[n0 + nf*16 + l16];
        acc[nf] = (f32x4){bv,bv,bv,bv};
    }

    for (int ks = 0; ks < 8; ks++) {
        const bf16x8 a0 = *(const bf16x8*)&Ob[(rowbase + l16)*DMODEL + ks*32 + quad*8];
        #pragma unroll
        for (int nf = 0; nf < 4; nf++) {
            const int n = nf*16 + l16;
            const bf16x8 bfr = *(const bf16x8*)&Bs[n*256 + 8*((ks*4 + quad) ^ (n & 7))];
            acc[nf] = __builtin_amdgcn_mfma_f32_16x16x32_bf16(a0, bfr, acc[nf], 0, 0, 0);
        }
    }

    const float g  = 1.f / (1.f + __expf(-gatep[0]));
    const float og = 1.f - g;

    #pragma unroll
    for (int nf = 0; nf < 4; nf++) {
        const int col = n0 + nf*16 + l16;
        #pragma unroll
        for (int r = 0; r < 4; r++) {
            const int row = rowbase + quad*4 + r;
            const float xv  = X [row*DMODEL + col];
            const float pev = PE[row*DMODEL + col];
            Out[row*DMODEL + col] = xv + og * pev + g * acc[nf][r];
        }
    }
}

// ---------------------------------------------------------------------------
extern "C" void kernel_launch(void* const* d_in, const int* in_sizes, int n_in,
                              void* d_out, int out_size, void* d_ws, size_t ws_size,
                              hipStream_t stream)
{
    const float* x    = (const float*)d_in[0];
    const float* pe   = (const float*)d_in[1];
    const float* Wq   = (const float*)d_in[2];
    const float* bq   = (const float*)d_in[3];
    const float* Wk   = (const float*)d_in[4];
    const float* bk   = (const float*)d_in[5];
    const float* Wo   = (const float*)d_in[6];
    const float* bo   = (const float*)d_in[7];
    const float* bt   = (const float*)d_in[8];
    const float* gate = (const float*)d_in[9];
    float* out = (float*)d_out;

    char* w = (char*)d_ws;
    const size_t MB = 1024u*1024u;
    unsigned short* Qb  = (unsigned short*)(w);               // 4 MB
    unsigned short* Kb  = (unsigned short*)(w + 4*MB);        // 4 MB
    unsigned short* Vtb = (unsigned short*)(w + 8*MB);        // 4 MB
    unsigned short* Xb  = (unsigned short*)(w + 12*MB);       // 4 MB
    float*          Pb3 = (float*)(w + 16*MB);                // 240 KB (rsvd 256K)
    unsigned short* Wqb = (unsigned short*)(w + 16*MB + 256u*1024);  // 128 KB
    unsigned short* Wkb = (unsigned short*)(w + 16*MB + 384u*1024);  // 128 KB
    unsigned short* Wob = (unsigned short*)(w + 16*MB + 512u*1024);  // 128 KB
    unsigned short* Ob  = (unsigned short*)(w + 17*MB);       // 4 MB

    prep<<<dim3(16, 32), 256, 0, stream>>>(
        x, Vtb, Xb, bt, Pb3, Wq, Wk, Wo, Wqb, Wkb, Wob);

    gemm_proj_mfma<<<dim3(DMODEL/64, NROWS/128, 2), 256, 0, stream>>>(
        Xb, Wqb, bq, Wkb, bk, Qb, Kb);

    attn_mfma<<<dim3(16, 32), 256, 0, stream>>>(
        Qb, Kb, Vtb, Pb3, Ob);

    gemm_out_mfma<<<dim3(DMODEL/64, NROWS/64), 256, 0, stream>>>(
        Ob, Wob, bo, x, pe, gate, out);
}